// Round 14
// baseline (3690.751 us; speedup 1.0000x reference)
//
#include <hip/hip_runtime.h>
#include <hip/hip_bf16.h>

#define B_   4
#define LQ_  4096
#define LS_  4096
#define DH_  1024
#define NT_  16
#define NTH  512

typedef __bf16 bf16x8 __attribute__((ext_vector_type(8)));
typedef float  f32x4  __attribute__((ext_vector_type(4)));
typedef float  f32x16 __attribute__((ext_vector_type(16)));
typedef unsigned char u8;
typedef unsigned int u32;
typedef unsigned short u16;

#define WAITV0() asm volatile("s_waitcnt vmcnt(0)" ::: "memory")
#define WAITL()  asm volatile("s_waitcnt lgkmcnt(0)" ::: "memory")
#define SCHEDB() __builtin_amdgcn_sched_barrier(0)
#define BAR()    __builtin_amdgcn_s_barrier()

__device__ __forceinline__ void glds16(const void* g, void* l) {
  __builtin_amdgcn_global_load_lds(
      (const __attribute__((address_space(1))) u32*)g,
      (__attribute__((address_space(3))) u32*)l, 16, 0, 0);
}
__device__ __forceinline__ u16 f2bf(float f) {
  union { __bf16 h; u16 u; } cv; cv.h = (__bf16)f; return cv.u;
}

// ================= cvt kernels (new path) =================
// Kf2 unit: ((b)*8M) + (((t*16 + c)*32) + w*4 + kkl)*1024 ; lane l: S[t*256+w*32+(l&31)][c*64+kkl*16+(l>>5)*8+e]
// Vf2 unit: ((b)*8M) + (((t*16 + ks)*32) + w*4 + ns)*1024 ; lane l: S[t*256+ks*16+(l>>5)*8+e][w*128+ns*32+(l&31)]
// Qf  unit: ((b)*8M) + (((qt*16 + c)*8) + kkl*2 + qf)*1024 ; lane l: Q[qt*64+qf*32+(l&31)][c*64+kkl*16+(l>>5)*8+e]
__global__ __launch_bounds__(256) void scvt_kernel(const float* __restrict__ S,
                                                   u8* __restrict__ Kf,
                                                   u8* __restrict__ Vf)
{
  __shared__ u16 tile[64][72];
  const int b  = blockIdx.z;
  const int dt = blockIdx.y;   // 0..15
  const int st = blockIdx.x;   // 0..63
  const int tid = threadIdx.x;
  const int t  = st >> 2;
  const float* Sbase = S + ((size_t)b*LS_ + (size_t)st*64)*DH_ + dt*64;

  #pragma unroll
  for (int k = 0; k < 4; ++k) {
    int fi  = tid + k*256;
    int row = fi >> 4;
    int c4  = fi & 15;
    float4 v = *reinterpret_cast<const float4*>(Sbase + (size_t)row*DH_ + c4*4);
    ushort4 h;
    h.x = f2bf(v.x); h.y = f2bf(v.y); h.z = f2bf(v.z); h.w = f2bf(v.w);
    *reinterpret_cast<ushort4*>(&tile[row][c4*4]) = h;
  }
  __syncthreads();

  // Kf2
  #pragma unroll
  for (int h2 = 0; h2 < 2; ++h2) {
    int u    = tid + h2*256;
    int blk  = u >> 6;
    int wloc = blk >> 2;
    int kkl  = blk & 3;
    int lane = u & 63;
    int srow = wloc*32 + (lane & 31);
    int scol = kkl*16 + (lane >> 5)*8;
    ushort4 h0 = *reinterpret_cast<const ushort4*>(&tile[srow][scol]);
    ushort4 h1 = *reinterpret_cast<const ushort4*>(&tile[srow][scol+4]);
    int w_g = (st & 3)*2 + wloc;
    u8* dst = Kf + (size_t)b*8388608 +
              ((((size_t)t*16 + dt)*32) + w_g*4 + kkl)*1024 + lane*16;
    *reinterpret_cast<ushort4*>(dst)     = h0;
    *reinterpret_cast<ushort4*>(dst + 8) = h1;
  }

  // Vf2
  #pragma unroll
  for (int h2 = 0; h2 < 2; ++h2) {
    int u    = tid + h2*256;
    int blk  = u >> 6;
    int ksl  = blk >> 1;        // 0..3
    int nsl  = blk & 1;         // 0..1
    int lane = u & 63;
    int srow = ksl*16 + (lane >> 5)*8;
    int dcol = nsl*32 + (lane & 31);
    ushort4 h0, h1;
    h0.x = tile[srow+0][dcol]; h0.y = tile[srow+1][dcol];
    h0.z = tile[srow+2][dcol]; h0.w = tile[srow+3][dcol];
    h1.x = tile[srow+4][dcol]; h1.y = tile[srow+5][dcol];
    h1.z = tile[srow+6][dcol]; h1.w = tile[srow+7][dcol];
    int ks = (st & 3)*4 + ksl;
    int w_g = dt >> 1;
    int ns  = (dt & 1)*2 + nsl;
    u8* dst = Vf + (size_t)b*8388608 +
              ((((size_t)t*16 + ks)*32) + w_g*4 + ns)*1024 + lane*16;
    *reinterpret_cast<ushort4*>(dst)     = h0;
    *reinterpret_cast<ushort4*>(dst + 8) = h1;
  }
}

__global__ __launch_bounds__(256) void qcvt_kernel(const float* __restrict__ Q,
                                                   u8* __restrict__ Qf)
{
  __shared__ u16 tile[64][72];
  const int b  = blockIdx.z;
  const int dt = blockIdx.y;   // 0..15
  const int qt = blockIdx.x;   // 0..63
  const int tid = threadIdx.x;
  const float* Qbase = Q + ((size_t)b*LQ_ + (size_t)qt*64)*DH_ + dt*64;

  #pragma unroll
  for (int k = 0; k < 4; ++k) {
    int fi  = tid + k*256;
    int row = fi >> 4;
    int c4  = fi & 15;
    float4 v = *reinterpret_cast<const float4*>(Qbase + (size_t)row*DH_ + c4*4);
    ushort4 h;
    h.x = f2bf(v.x); h.y = f2bf(v.y); h.z = f2bf(v.z); h.w = f2bf(v.w);
    *reinterpret_cast<ushort4*>(&tile[row][c4*4]) = h;
  }
  __syncthreads();

  #pragma unroll
  for (int h2 = 0; h2 < 2; ++h2) {
    int u    = tid + h2*256;
    int blk  = u >> 6;          // 0..7
    int kkl  = blk >> 1;
    int qf   = blk & 1;
    int lane = u & 63;
    int row  = qf*32 + (lane & 31);
    int col  = kkl*16 + (lane >> 5)*8;
    ushort4 h0 = *reinterpret_cast<const ushort4*>(&tile[row][col]);
    ushort4 h1 = *reinterpret_cast<const ushort4*>(&tile[row][col+4]);
    u8* dst = Qf + (size_t)b*8388608 +
              ((((size_t)qt*16 + dt)*8) + kkl*2 + qf)*1024 + lane*16;
    *reinterpret_cast<ushort4*>(dst)     = h0;
    *reinterpret_cast<ushort4*>(dst + 8) = h1;
  }
}

// ================= main: glds-pipelined flash attention =================
// 8 waves; QK: wave w owns s-slice [w*32,w*32+32), C[64q][32s] via 32x32x16.
// PV: wave w owns d [w*128,+128), 32x32x16, Oacc[2 qh][4 dsub].
// K/V staged per-wave via global_load_lds (private LDS dbuf, no barriers);
// Q streamed to regs from Qf (ring of 8 units). 2 plds barriers/tile.
__global__ __launch_bounds__(NTH, 2) void attn_glds(
    const u8* __restrict__ Qf, const u8* __restrict__ Kf,
    const u8* __restrict__ Vf, float* __restrict__ Og)
{
  __shared__ __align__(16) u8 kst[65536];
  __shared__ __align__(16) u8 vst[65536];
  __shared__ __align__(16) u8 plds[32768];

  const int tid = threadIdx.x;
  const int w  = tid >> 6;
  const int l  = tid & 63;
  const int sl = l & 31;
  const int sh = l >> 5;

  const int n    = blockIdx.x;
  const int xcd  = n & 7;
  const int slot = n >> 3;
  const int b    = xcd >> 1;
  const int qt   = (xcd & 1)*32 + slot;

  const u8* qfb = Qf + (size_t)b*8388608 + (size_t)qt*131072;
  const u8* kfb = Kf + (size_t)b*8388608;
  const u8* vfb = Vf + (size_t)b*8388608;
  u8* kmy = kst + w*4096;
  u8* vmy = vst + w*4096;

  auto kgl = [&](int t, int c, int buf) {
    const u8* src = kfb + ((((size_t)t*16 + c)*32) + w*4)*1024 + l*16;
    #pragma unroll
    for (int kkl = 0; kkl < 4; ++kkl)
      glds16(src + kkl*1024, kmy + buf*32768 + kkl*1024);
  };
  auto vgl = [&](int t, int ks, int buf) {
    const u8* src = vfb + ((((size_t)t*16 + ks)*32) + w*4)*1024 + l*16;
    #pragma unroll
    for (int ns = 0; ns < 4; ++ns)
      glds16(src + ns*1024, vmy + buf*32768 + ns*1024);
  };
  auto qld = [&](int c, int kkl, int qf) -> bf16x8 {
    return *reinterpret_cast<const bf16x8*>(
        qfb + (((size_t)c*8) + kkl*2 + qf)*1024 + l*16);
  };
  auto bkr = [&](int kkl, int buf) -> bf16x8 {
    return *reinterpret_cast<const bf16x8*>(kmy + buf*32768 + kkl*1024 + l*16);
  };
  auto bvr = [&](int ns, int buf) -> bf16x8 {
    return *reinterpret_cast<const bf16x8*>(vmy + buf*32768 + ns*1024 + l*16);
  };
  auto ldP = [&](int qh, int ks) -> bf16x8 {
    int q = qh*32 + sl;
    return *reinterpret_cast<const bf16x8*>(
        plds + q*512 + ((ks*32 + sh*16) ^ ((q & 7) << 4)));
  };

  f32x16 Oacc[2][4];
  #pragma unroll
  for (int i = 0; i < 2; ++i)
    #pragma unroll
    for (int j = 0; j < 4; ++j)
      #pragma unroll
      for (int r = 0; r < 16; ++r) Oacc[i][j][r] = 0.f;
  float l_run0[16], l_run1[16];
  #pragma unroll
  for (int r = 0; r < 16; ++r) { l_run0[r] = 0.f; l_run1[r] = 0.f; }

  f32x16 qk0, qk1;
  bf16x8 aq[8];
  const float SCL = 0.04508422f;   // (1/32)*log2(e)
  const int s2 = (w*32 + sl)*2;

  // prologue: K(0,0) -> kst buf0; aq chunk 0
  kgl(0, 0, 0);
  #pragma unroll
  for (int kkl = 0; kkl < 4; ++kkl) {
    aq[kkl*2+0] = qld(0, kkl, 0);
    aq[kkl*2+1] = qld(0, kkl, 1);
  }
  #pragma unroll
  for (int r = 0; r < 16; ++r) { qk0[r] = 0.f; qk1[r] = 0.f; }

  // ================= period 0: QK(0) only =================
  #pragma unroll
  for (int c = 0; c < 16; ++c) {
    const int buf = c & 1;
    WAITV0(); SCHEDB();
    if (c < 15) kgl(0, c + 1, buf ^ 1);
    else { kgl(1, 0, buf ^ 1); vgl(0, 0, buf ^ 1); }
    const int cn = (c + 1) & 15;
    #pragma unroll
    for (int kkl = 0; kkl < 4; ++kkl) {
      bf16x8 bk = bkr(kkl, buf);
      __builtin_amdgcn_s_setprio(1);
      qk0 = __builtin_amdgcn_mfma_f32_32x32x16_bf16(aq[kkl*2+0], bk, qk0, 0, 0, 0);
      qk1 = __builtin_amdgcn_mfma_f32_32x32x16_bf16(aq[kkl*2+1], bk, qk1, 0, 0, 0);
      __builtin_amdgcn_s_setprio(0);
      aq[kkl*2+0] = qld(cn, kkl, 0);
      aq[kkl*2+1] = qld(cn, kkl, 1);
    }
  }

  // ================= periods t = 1..15: softmax(t-1) + fused QK(t)/PV(t-1) ==========
  #pragma unroll 1
  for (int t = 1; t < NT_; ++t) {
    BAR();   // all waves' plds reads of P(t-2) done
    #pragma unroll
    for (int r = 0; r < 16; ++r) {
      int qrow = (r & 3) + 8*(r >> 2) + 4*sh;
      {
        float p = exp2f(qk0[r] * SCL);
        int q = qrow;
        *reinterpret_cast<__bf16*>(plds + q*512 + (s2 ^ ((q & 7) << 4))) = (__bf16)p;
        float v = p;
        v += __shfl_xor(v, 1); v += __shfl_xor(v, 2); v += __shfl_xor(v, 4);
        v += __shfl_xor(v, 8); v += __shfl_xor(v, 16);
        l_run0[r] += v;
      }
      {
        float p = exp2f(qk1[r] * SCL);
        int q = 32 + qrow;
        *reinterpret_cast<__bf16*>(plds + q*512 + (s2 ^ ((q & 7) << 4))) = (__bf16)p;
        float v = p;
        v += __shfl_xor(v, 1); v += __shfl_xor(v, 2); v += __shfl_xor(v, 4);
        v += __shfl_xor(v, 8); v += __shfl_xor(v, 16);
        l_run1[r] += v;
      }
    }
    WAITL();
    BAR();   // P(t-1) visible

    #pragma unroll
    for (int r = 0; r < 16; ++r) { qk0[r] = 0.f; qk1[r] = 0.f; }

    #pragma unroll
    for (int c = 0; c < 16; ++c) {
      const int buf = c & 1;
      WAITV0(); SCHEDB();
      if (c < 15)      { kgl(t, c + 1, buf ^ 1); vgl(t - 1, c + 1, buf ^ 1); }
      else             { if (t < 15) kgl(t + 1, 0, buf ^ 1); vgl(t, 0, buf ^ 1); }
      const int cn = (c + 1) & 15;
      // QK chunk c
      #pragma unroll
      for (int kkl = 0; kkl < 4; ++kkl) {
        bf16x8 bk = bkr(kkl, buf);
        __builtin_amdgcn_s_setprio(1);
        qk0 = __builtin_amdgcn_mfma_f32_32x32x16_bf16(aq[kkl*2+0], bk, qk0, 0, 0, 0);
        qk1 = __builtin_amdgcn_mfma_f32_32x32x16_bf16(aq[kkl*2+1], bk, qk1, 0, 0, 0);
        __builtin_amdgcn_s_setprio(0);
        aq[kkl*2+0] = qld(cn, kkl, 0);
        aq[kkl*2+1] = qld(cn, kkl, 1);
      }
      // PV chunk c (tile t-1)
      bf16x8 pa0 = ldP(0, c);
      bf16x8 pa1 = ldP(1, c);
      __builtin_amdgcn_s_setprio(1);
      #pragma unroll
      for (int ns = 0; ns < 4; ++ns) {
        bf16x8 bv = bvr(ns, buf);
        Oacc[0][ns] = __builtin_amdgcn_mfma_f32_32x32x16_bf16(pa0, bv, Oacc[0][ns], 0, 0, 0);
        Oacc[1][ns] = __builtin_amdgcn_mfma_f32_32x32x16_bf16(pa1, bv, Oacc[1][ns], 0, 0, 0);
      }
      __builtin_amdgcn_s_setprio(0);
    }
  }

  // ================= softmax(15) =================
  BAR();
  #pragma unroll
  for (int r = 0; r < 16; ++r) {
    int qrow = (r & 3) + 8*(r >> 2) + 4*sh;
    {
      float p = exp2f(qk0[r] * SCL);
      int q = qrow;
      *reinterpret_cast<__bf16*>(plds + q*512 + (s2 ^ ((q & 7) << 4))) = (__bf16)p;
      float v = p;
      v += __shfl_xor(v, 1); v += __shfl_xor(v, 2); v += __shfl_xor(v, 4);
      v += __shfl_xor(v, 8); v += __shfl_xor(v, 16);
      l_run0[r] += v;
    }
    {
      float p = exp2f(qk1[r] * SCL);
      int q = 32 + qrow;
      *reinterpret_cast<__bf16*>(plds + q*512 + (s2 ^ ((q & 7) << 4))) = (__bf16)p;
      float v = p;
      v += __shfl_xor(v, 1); v += __shfl_xor(v, 2); v += __shfl_xor(v, 4);
      v += __shfl_xor(v, 8); v += __shfl_xor(v, 16);
      l_run1[r] += v;
    }
  }
  WAITL();
  BAR();

  // ================= epilogue period: PV(15) only =================
  #pragma unroll
  for (int c = 0; c < 16; ++c) {
    const int buf = c & 1;
    WAITV0(); SCHEDB();
    if (c < 15) vgl(15, c + 1, buf ^ 1);
    bf16x8 pa0 = ldP(0, c);
    bf16x8 pa1 = ldP(1, c);
    __builtin_amdgcn_s_setprio(1);
    #pragma unroll
    for (int ns = 0; ns < 4; ++ns) {
      bf16x8 bv = bvr(ns, buf);
      Oacc[0][ns] = __builtin_amdgcn_mfma_f32_32x32x16_bf16(pa0, bv, Oacc[0][ns], 0, 0, 0);
      Oacc[1][ns] = __builtin_amdgcn_mfma_f32_32x32x16_bf16(pa1, bv, Oacc[1][ns], 0, 0, 0);
    }
    __builtin_amdgcn_s_setprio(0);
  }
  BAR();   // plds reads done

  // ================= l combine + O write =================
  float* lred = (float*)plds;
  if (sl == 0) {
    #pragma unroll
    for (int r = 0; r < 16; ++r) {
      int qrow = (r & 3) + 8*(r >> 2) + 4*sh;
      lred[w*64 + qrow]      = l_run0[r];
      lred[w*64 + 32 + qrow] = l_run1[r];
    }
  }
  WAITL();
  BAR();

  float* Ob = Og + ((size_t)b*LQ_ + (size_t)qt*64)*DH_;
  #pragma unroll
  for (int qh = 0; qh < 2; ++qh)
    #pragma unroll
    for (int r = 0; r < 16; ++r) {
      int q = qh*32 + (r & 3) + 8*(r >> 2) + 4*sh;
      float s = 0.f;
      #pragma unroll
      for (int k2 = 0; k2 < 8; ++k2) s += lred[k2*64 + q];
      float rinv = 1.0f / s;
      #pragma unroll
      for (int ds = 0; ds < 4; ++ds)
        Ob[(size_t)q*DH_ + w*128 + ds*32 + sl] = Oacc[qh][ds][r] * rinv;
    }
}

// =====================================================================
// ============ r11 fallback path (64 MB ws), kept verbatim ============
// =====================================================================
__device__ __forceinline__ bf16x8 cvt8(f32x4 a, f32x4 b) {
  bf16x8 r;
  r[0] = (__bf16)a[0]; r[1] = (__bf16)a[1]; r[2] = (__bf16)a[2]; r[3] = (__bf16)a[3];
  r[4] = (__bf16)b[0]; r[5] = (__bf16)b[1]; r[6] = (__bf16)b[2]; r[7] = (__bf16)b[3];
  return r;
}

__global__ __launch_bounds__(256) void cvt_r11(const float* __restrict__ S,
                                               u8* __restrict__ Kf,
                                               u8* __restrict__ Vf)
{
  __shared__ u16 tile[64][72];
  const int b  = blockIdx.z;
  const int dt = blockIdx.y;
  const int st = blockIdx.x;
  const int tid = threadIdx.x;
  const int t  = st >> 2;
  const float* Sbase = S + ((size_t)b*LS_ + (size_t)st*64)*DH_ + dt*64;

  #pragma unroll
  for (int k = 0; k < 4; ++k) {
    int fi  = tid + k*256;
    int row = fi >> 4;
    int c4  = fi & 15;
    float4 v = *reinterpret_cast<const float4*>(Sbase + (size_t)row*DH_ + c4*4);
    ushort4 h;
    h.x = f2bf(v.x); h.y = f2bf(v.y); h.z = f2bf(v.z); h.w = f2bf(v.w);
    *reinterpret_cast<ushort4*>(&tile[row][c4*4]) = h;
  }
  __syncthreads();

  #pragma unroll
  for (int h2 = 0; h2 < 2; ++h2) {
    int u    = tid + h2*256;
    int blk  = u >> 6;
    int wloc = blk >> 2;
    int kkl  = blk & 3;
    int lane = u & 63;
    int srow = wloc*32 + (lane & 31);
    int scol = kkl*16 + (lane >> 5)*8;
    ushort4 h0 = *reinterpret_cast<const ushort4*>(&tile[srow][scol]);
    ushort4 h1 = *reinterpret_cast<const ushort4*>(&tile[srow][scol+4]);
    int w_g  = (st & 3)*2 + wloc;
    int kk_g = dt*4 + kkl;
    u8* dst = Kf + (size_t)(((b*16 + t)*8 + w_g)*64 + kk_g)*1024 + lane*16;
    *reinterpret_cast<ushort4*>(dst)     = h0;
    *reinterpret_cast<ushort4*>(dst + 8) = h1;
  }

  #pragma unroll
  for (int h2 = 0; h2 < 2; ++h2) {
    int u    = tid + h2*256;
    int blk  = u >> 6;
    int ksl  = blk >> 2;
    int nfl  = blk & 3;
    int lane = u & 63;
    int lg   = (lane >> 4) & 3, lr = lane & 15;
    int srow = ksl*32 + lg*8;
    int dcol = nfl*16 + lr;
    ushort4 h0, h1;
    h0.x = tile[srow+0][dcol]; h0.y = tile[srow+1][dcol];
    h0.z = tile[srow+2][dcol]; h0.w = tile[srow+3][dcol];
    h1.x = tile[srow+4][dcol]; h1.y = tile[srow+5][dcol];
    h1.z = tile[srow+6][dcol]; h1.w = tile[srow+7][dcol];
    int w_g = dt >> 1;
    int i_g = ((st & 3)*2 + ksl)*8 + (dt & 1)*4 + nfl;
    u8* dst = Vf + (size_t)(((b*16 + t)*8 + w_g)*64 + i_g)*1024 + lane*16;
    *reinterpret_cast<ushort4*>(dst)     = h0;
    *reinterpret_cast<ushort4*>(dst + 8) = h1;
  }
}

__global__ __launch_bounds__(NTH, 1) void attn_r11(
    const float* __restrict__ Qg,
    const u8* __restrict__ Kf,
    const u8* __restrict__ Vf,
    float* __restrict__ Og)
{
  __shared__ __align__(16) u8 qlds[131072];
  __shared__ __align__(16) u8 plds[32768];

  const int tid = threadIdx.x;
  const int w  = tid >> 6;
  const int l  = tid & 63;
  const int lg = l >> 4;
  const int lr = l & 15;
  const int sl = l & 31;
  const int sh = l >> 5;

  const int n    = blockIdx.x;
  const int xcd  = n & 7;
  const int slot = n >> 3;
  const int b    = xcd >> 1;
  const int qt   = (xcd & 1)*32 + slot;
  const int off  = slot & 7;

  const float* Qbase = Qg + ((size_t)b*LQ_ + (size_t)qt*64)*DH_;
  const u8* kptr = Kf + (size_t)b*8388608 + (size_t)w*65536 + l*16;
  const u8* vptr = Vf + (size_t)b*8388608 + (size_t)w*65536 + l*16;

  bf16x8 bk[4], bv[4];
  auto ldU = [&](const u8* base, int unit) -> bf16x8 {
    return *reinterpret_cast<const bf16x8*>(base + unit*1024);
  };
  auto ldP = [&](int mq, int ks) -> bf16x8 {
    int q = mq*16 + lr;
    return *reinterpret_cast<const bf16x8*>(
        plds + q*512 + ((ks*64 + lg*16) ^ ((q & 7) << 4)));
  };
  auto ldA = [&](int kk, int qf) -> bf16x8 {
    return *reinterpret_cast<const bf16x8*>(qlds + qf*65536 + kk*1024 + l*16);
  };

  bk[0] = ldU(kptr, off*8 + 0); bk[1] = ldU(kptr, off*8 + 1);
  bk[2] = ldU(kptr, off*8 + 2); bk[3] = ldU(kptr, off*8 + 3);

  #pragma unroll
  for (int it = 0; it < 16; ++it) {
    int u  = tid + it*NTH;
    int qf = u >> 12;
    int kk = (u >> 6) & 63;
    int ll = u & 63;
    int q  = qf*32 + (ll & 31);
    int d  = kk*16 + (ll >> 5)*8;
    const float* p = Qbase + (size_t)q*DH_ + d;
    f32x4 v0 = *reinterpret_cast<const f32x4*>(p);
    f32x4 v1 = *reinterpret_cast<const f32x4*>(p + 4);
    *reinterpret_cast<bf16x8*>(qlds + (size_t)u*16) = cvt8(v0, v1);
  }

  f32x4 Oacc[4][8];
  #pragma unroll
  for (int i = 0; i < 4; ++i)
    #pragma unroll
    for (int j = 0; j < 8; ++j)
      Oacc[i][j] = (f32x4){0.f, 0.f, 0.f, 0.f};
  f32x4 lacc[4];
  #pragma unroll
  for (int i = 0; i < 4; ++i) lacc[i] = (f32x4){0.f, 0.f, 0.f, 0.f};

  bf16x8 ones;
  #pragma unroll
  for (int e = 0; e < 8; ++e) ones[e] = (__bf16)1.0f;

  f32x16 qk0, qk1;
  const float SCL = 0.04508422f;

  WAITL();
  BAR();

  bf16x8 aqA0 = ldA(off*8, 0);
  bf16x8 aqA1 = ldA(off*8, 1);

  #pragma unroll
  for (int r = 0; r < 16; ++r) { qk0[r] = 0.f; qk1[r] = 0.f; }
  #pragma unroll 1
  for (int seg = 0; seg < 8; ++seg) {
    const int ibe = (seg + off) & 7;
    const int ibn = (ibe + 1) & 7;
    const u8* kP = (seg < 7) ? kptr : kptr + 524288;
    #pragma unroll
    for (int j = 0; j < 8; ++j) {
      const int nu = (j < 7) ? (ibe*8 + j + 1) : (ibn*8);
      bf16x8 aqN0 = ldA(nu, 0);
      bf16x8 aqN1 = ldA(nu, 1);
      __builtin_amdgcn_s_setprio(1);
      qk0 = __builtin_amdgcn_mfma_f32_32x32x16_bf16(aqA0, bk[j & 3], qk0, 0, 0, 0);
      qk1 = __builtin_amdgcn_mfma_f32_32x32x16_bf16(aqA1, bk[j & 3], qk1, 0, 0, 0);
      __builtin_amdgcn_s_setprio(0);
      if (j < 4) bk[j] = ldU(kptr, ibe*8 + j + 4);
      else {
        bk[j - 4] = ldU(kP, ibn*8 + j - 4);
        if (seg == 7) bv[j - 4] = ldU(vptr, ibn*8 + j - 4);
      }
      aqA0 = aqN0; aqA1 = aqN1;
    }
  }

  #pragma unroll 1
  for (int t = 1; t < NT_; ++t) {
    BAR();
    #pragma unroll
    for (int r = 0; r < 16; ++r) {
      int qrow = (r & 3) + 8*(r >> 2) + 4*sh;
      int s    = w*32 + sl;
      {
        float p = exp2f(qk0[r] * SCL);
        int q = qrow;
        *reinterpret_cast<__bf16*>(plds + q*512 + ((s*2) ^ ((q & 7) << 4))) = (__bf16)p;
      }
      {
        float p = exp2f(qk1[r] * SCL);
        int q = 32 + qrow;
        *reinterpret_cast<__bf16*>(plds + q*512 + ((s*2) ^ ((q & 7) << 4))) = (__bf16)p;
      }
    }
    WAITL();
    BAR();

    #pragma unroll
    for (int r = 0; r < 16; ++r) { qk0[r] = 0.f; qk1[r] = 0.f; }

    const u8* kT = kptr + (size_t)t*524288;
    const u8* vT = vptr + (size_t)(t-1)*524288;
    bf16x8 pa0, pa1, pa2, pa3;

    #pragma unroll 1
    for (int seg = 0; seg < 8; ++seg) {
      const int ibe = (seg + off) & 7;
      const int ibn = (ibe + 1) & 7;
      const u8* kP = (seg < 7) ? kT : kT + 524288;
      const u8* vP = (seg < 7) ? vT : vT + 524288;
      #pragma unroll
      for (int j = 0; j < 8; ++j) {
        const int nu = (j < 7) ? (ibe*8 + j + 1) : (ibn*8);
        bf16x8 aqN0 = ldA(nu, 0);
        bf16x8 aqN1 = ldA(nu, 1);
        if (j == 0) {
          pa0 = ldP(0, ibe); pa1 = ldP(1, ibe); pa2 = ldP(2, ibe); pa3 = ldP(3, ibe);
          if (ibe == w) {
            lacc[0] = __builtin_amdgcn_mfma_f32_16x16x32_bf16(pa0, ones, lacc[0], 0, 0, 0);
            lacc[1] = __builtin_amdgcn_mfma_f32_16x16x32_bf16(pa1, ones, lacc[1], 0, 0, 0);
            lacc[2] = __builtin_amdgcn_mfma_f32_16x16x32_bf16(pa2, ones, lacc[2], 0, 0, 0);
            lacc[3] = __builtin_amdgcn_mfma_f32_16x16x32_bf16(pa3, ones, lacc[3], 0, 0, 0);
          }
        }
        __builtin_amdgcn_s_setprio(1);
        qk0 = __builtin_amdgcn_mfma_f32_32x32x16_bf16(aqA0, bk[j & 3], qk0, 0, 0, 0);
        qk1 = __builtin_amdgcn_mfma_f32_32x32x16_bf16(aqA1, bk[j & 3], qk1, 0, 0, 0);
        Oacc[0][j] = __builtin_amdgcn_mfma_f32_16x16x32_bf16(pa0, bv[j & 3], Oacc[0][j], 0, 0, 0);
        Oacc[1][j] = __builtin_amdgcn_mfma_f32_16x16x32_bf16(pa1, bv[j & 3], Oacc[1][j], 0, 0, 0);
        Oacc[2][j] = __builtin_amdgcn_mfma_f32_16x16x32_bf16(pa2, bv[j & 3], Oacc[2][j], 0, 0, 0);
        Oacc[3][j] = __builtin_amdgcn_mfma_f32_16x16x32_bf16(pa3, bv[j & 3], Oacc[3][j], 0, 0, 0);
        __builtin_amdgcn_s_setprio(0);
        if (j < 4) {
          bk[j] = ldU(kT, ibe*8 + j + 4);
          bv[j] = ldU(vT, ibe*8 + j + 4);
        } else {
          bk[j - 4] = ldU(kP, ibn*8 + j - 4);
          bv[j - 4] = ldU(vP, ibn*8 + j - 4);
        }
        aqA0 = aqN0; aqA1 = aqN1;
      }
    }
  }

  BAR();
  #pragma unroll
  for (int r = 0; r < 16; ++r) {
    int qrow = (r & 3) + 8*(r >> 2) + 4*sh;
    int s    = w*32 + sl;
    {
      float p = exp2f(qk0[r] * SCL);
      int q = qrow;
      *reinterpret_cast<__bf16*>(plds + q*512 + ((s*2) ^ ((q & 7) << 4))) = (__bf16)p;
    }
    {
      float p = exp2f(qk1[r] * SCL);
      int q = 32 + qrow;
      *reinterpret_cast<__bf16*>(plds + q*512 + ((s*2) ^ ((q & 7) << 4))) = (__bf16)p;
    }
  }
  WAITL();
  BAR();

  {
    const u8* vT = vptr + (size_t)(NT_-1)*524288;
    bf16x8 pa0, pa1, pa2, pa3;
    #pragma unroll 1
    for (int seg = 0; seg < 8; ++seg) {
      const int ibe = (seg + off) & 7;
      const int ibn = (ibe + 1) & 7;
      #pragma unroll
      for (int j = 0; j < 8; ++j) {
        if (j == 0) {
          pa0 = ldP(0, ibe); pa1 = ldP(1, ibe); pa2 = ldP(2, ibe); pa3 = ldP(3, ibe);
          if (ibe == w) {
            lacc[0] = __builtin_amdgcn_mfma_f32_16x16x32_bf16(pa0, ones, lacc[0], 0, 0, 0);
            lacc[1] = __builtin_amdgcn_mfma_f32_16x16x32_bf16(pa1, ones, lacc[1], 0, 0, 0);
            lacc[2] = __builtin_amdgcn_mfma_f32_16x16x32_bf16(pa2, ones, lacc[2], 0, 0, 0);
            lacc[3] = __builtin_amdgcn_mfma_f32_16x16x32_bf16(pa3, ones, lacc[3], 0, 0, 0);
          }
        }
        __builtin_amdgcn_s_setprio(1);
        Oacc[0][j] = __builtin_amdgcn_mfma_f32_16x16x32_bf16(pa0, bv[j & 3], Oacc[0][j], 0, 0, 0);
        Oacc[1][j] = __builtin_amdgcn_mfma_f32_16x16x32_bf16(pa1, bv[j & 3], Oacc[1][j], 0, 0, 0);
        Oacc[2][j] = __builtin_amdgcn_mfma_f32_16x16x32_bf16(pa2, bv[j & 3], Oacc[2][j], 0, 0, 0);
        Oacc[3][j] = __builtin_amdgcn_mfma_f32_16x16x32_bf16(pa3, bv[j & 3], Oacc[3][j], 0, 0, 0);
        __builtin_amdgcn_s_setprio(0);
        if (j < 4)        bv[j] = ldU(vT, ibe*8 + j + 4);
        else if (seg < 7) bv[j - 4] = ldU(vT, ibn*8 + j - 4);
      }
    }
  }
  BAR();

  float* lred = (float*)plds;
  if (lr == 0) {
    #pragma unroll
    for (int mq = 0; mq < 4; ++mq)
      #pragma unroll
      for (int j = 0; j < 4; ++j)
        lred[w*64 + mq*16 + lg*4 + j] = lacc[mq][j];
  }
  WAITL();
  BAR();

  float* Ob = Og + ((size_t)b*LQ_ + (size_t)qt*64)*DH_;
  #pragma unroll
  for (int mq = 0; mq < 4; ++mq)
    #pragma unroll
    for (int j = 0; j < 4; ++j) {
      int q = mq*16 + lg*4 + j;
      float s = 0.f;
      #pragma unroll
      for (int ww = 0; ww < 8; ++ww) s += lred[ww*64 + q];
      float rinv = 1.0f / s;
      #pragma unroll
      for (int nf = 0; nf < 8; ++nf)
        Ob[(size_t)q*DH_ + w*128 + nf*16 + lr] = Oacc[mq][nf][j] * rinv;
    }
}

// ---------------- correctness-only fallback ----------------
__global__ void attn_naive(const float* __restrict__ Q, const float* __restrict__ S,
                           float* __restrict__ O)
{
  const int row = blockIdx.x;
  const int b = row >> 12, q = row & 4095;
  const float* qp = Q + ((size_t)b*LQ_ + q)*DH_;
  const float* sp = S + (size_t)b*LS_*DH_;
  __shared__ float qs[DH_];
  __shared__ float osum[DH_];
  __shared__ float lsum;
  for (int i = threadIdx.x; i < DH_; i += 256) { qs[i] = qp[i]; osum[i] = 0.f; }
  if (threadIdx.x == 0) lsum = 0.f;
  __syncthreads();
  float lpart = 0.f;
  for (int s0 = threadIdx.x; s0 < LS_; s0 += 256) {
    const float* sr = sp + (size_t)s0*DH_;
    float dot = 0.f;
    for (int d = 0; d < DH_; ++d) dot += qs[d]*sr[d];
    float p = __expf(dot * 0.03125f);
    lpart += p;
    for (int d = 0; d < DH_; ++d) atomicAdd(&osum[d], p*sr[d]);
  }
  atomicAdd(&lsum, lpart);
  __syncthreads();
  float rinv = 1.0f / lsum;
  float* op = O + ((size_t)b*LQ_ + q)*DH_;
  for (int i = threadIdx.x; i < DH_; i += 256) op[i] = osum[i]*rinv;
}

extern "C" void kernel_launch(void* const* d_in, const int* in_sizes, int n_in,
                              void* d_out, int out_size, void* d_ws, size_t ws_size,
                              hipStream_t stream)
{
  const float* Q = (const float*)d_in[0];
  const float* S = (const float*)d_in[1];
  float* out = (float*)d_out;

  const size_t seg = (size_t)B_*8388608;        // 32 MiB per tensor
  const size_t need_new = 3*seg;                // Qf + Kf2 + Vf2 = 96 MiB
  const size_t need_old = 2*seg;                // 64 MiB

  if (ws_size >= need_new) {
    u8* Qf  = (u8*)d_ws;
    u8* Kf2 = Qf + seg;
    u8* Vf2 = Kf2 + seg;
    qcvt_kernel<<<dim3(64, 16, 4), 256, 0, stream>>>(Q, Qf);
    scvt_kernel<<<dim3(64, 16, 4), 256, 0, stream>>>(S, Kf2, Vf2);
    attn_glds<<<dim3(256), NTH, 0, stream>>>(Qf, Kf2, Vf2, out);
  } else if (ws_size >= need_old) {
    u8* Kf = (u8*)d_ws;
    u8* Vf = Kf + seg;
    cvt_r11<<<dim3(64, 16, 4), 256, 0, stream>>>(S, Kf, Vf);
    attn_r11<<<dim3(256), NTH, 0, stream>>>(Q, Kf, Vf, out);
  } else {
    attn_naive<<<dim3(B_*LQ_), 256, 0, stream>>>(Q, S, out);
  }
}

// Round 15
// 1469.703 us; speedup vs baseline: 2.5112x; 2.5112x over previous
//
#include <hip/hip_runtime.h>
#include <hip/hip_bf16.h>

#define B_   4
#define LQ_  4096
#define LS_  4096
#define DH_  1024
#define NT_  16
#define NTH  512

typedef __bf16 bf16x8 __attribute__((ext_vector_type(8)));
typedef float  f32x4  __attribute__((ext_vector_type(4)));
typedef float  f32x16 __attribute__((ext_vector_type(16)));
typedef unsigned char u8;
typedef unsigned int u32;
typedef unsigned short u16;

#define WAITV0() asm volatile("s_waitcnt vmcnt(0)" ::: "memory")
#define WAITL()  asm volatile("s_waitcnt lgkmcnt(0)" ::: "memory")
#define SCHEDB() __builtin_amdgcn_sched_barrier(0)
#define BAR()    __builtin_amdgcn_s_barrier()

__device__ __forceinline__ void glds16(const void* g, void* l) {
  __builtin_amdgcn_global_load_lds(
      (const __attribute__((address_space(1))) u32*)g,
      (__attribute__((address_space(3))) u32*)l, 16, 0, 0);
}
__device__ __forceinline__ u16 f2bf(float f) {
  union { __bf16 h; u16 u; } cv; cv.h = (__bf16)f; return cv.u;
}

// ================= cvt kernels (glds path) =================
__global__ __launch_bounds__(256) void scvt_kernel(const float* __restrict__ S,
                                                   u8* __restrict__ Kf,
                                                   u8* __restrict__ Vf)
{
  __shared__ u16 tile[64][72];
  const int b  = blockIdx.z;
  const int dt = blockIdx.y;   // 0..15
  const int st = blockIdx.x;   // 0..63
  const int tid = threadIdx.x;
  const int t  = st >> 2;
  const float* Sbase = S + ((size_t)b*LS_ + (size_t)st*64)*DH_ + dt*64;

  #pragma unroll
  for (int k = 0; k < 4; ++k) {
    int fi  = tid + k*256;
    int row = fi >> 4;
    int c4  = fi & 15;
    float4 v = *reinterpret_cast<const float4*>(Sbase + (size_t)row*DH_ + c4*4);
    ushort4 h;
    h.x = f2bf(v.x); h.y = f2bf(v.y); h.z = f2bf(v.z); h.w = f2bf(v.w);
    *reinterpret_cast<ushort4*>(&tile[row][c4*4]) = h;
  }
  __syncthreads();

  // Kf: unit (t,c=dt,w,kkl): lane l holds S[t*256+w*32+(l&31)][dt*64+kkl*16+(l>>5)*8+e]
  #pragma unroll
  for (int h2 = 0; h2 < 2; ++h2) {
    int u    = tid + h2*256;
    int blk  = u >> 6;
    int wloc = blk >> 2;
    int kkl  = blk & 3;
    int lane = u & 63;
    int srow = wloc*32 + (lane & 31);
    int scol = kkl*16 + (lane >> 5)*8;
    ushort4 h0 = *reinterpret_cast<const ushort4*>(&tile[srow][scol]);
    ushort4 h1 = *reinterpret_cast<const ushort4*>(&tile[srow][scol+4]);
    int w_g = (st & 3)*2 + wloc;
    u8* dst = Kf + (size_t)b*8388608 +
              ((((size_t)t*16 + dt)*32) + w_g*4 + kkl)*1024 + lane*16;
    *reinterpret_cast<ushort4*>(dst)     = h0;
    *reinterpret_cast<ushort4*>(dst + 8) = h1;
  }

  // Vf: unit (t,ks,w,ns): lane l holds S[t*256+ks*16+(l>>5)*8+e][w*128+ns*32+(l&31)]
  #pragma unroll
  for (int h2 = 0; h2 < 2; ++h2) {
    int u    = tid + h2*256;
    int blk  = u >> 6;
    int ksl  = blk >> 1;        // 0..3
    int nsl  = blk & 1;         // 0..1
    int lane = u & 63;
    int srow = ksl*16 + (lane >> 5)*8;
    int dcol = nsl*32 + (lane & 31);
    ushort4 h0, h1;
    h0.x = tile[srow+0][dcol]; h0.y = tile[srow+1][dcol];
    h0.z = tile[srow+2][dcol]; h0.w = tile[srow+3][dcol];
    h1.x = tile[srow+4][dcol]; h1.y = tile[srow+5][dcol];
    h1.z = tile[srow+6][dcol]; h1.w = tile[srow+7][dcol];
    int ks = (st & 3)*4 + ksl;
    int w_g = dt >> 1;
    int ns  = (dt & 1)*2 + nsl;
    u8* dst = Vf + (size_t)b*8388608 +
              ((((size_t)t*16 + ks)*32) + w_g*4 + ns)*1024 + lane*16;
    *reinterpret_cast<ushort4*>(dst)     = h0;
    *reinterpret_cast<ushort4*>(dst + 8) = h1;
  }
}

__global__ __launch_bounds__(256) void qcvt_kernel(const float* __restrict__ Q,
                                                   u8* __restrict__ Qf)
{
  __shared__ u16 tile[64][72];
  const int b  = blockIdx.z;
  const int dt = blockIdx.y;   // 0..15
  const int qt = blockIdx.x;   // 0..63
  const int tid = threadIdx.x;
  const float* Qbase = Q + ((size_t)b*LQ_ + (size_t)qt*64)*DH_ + dt*64;

  #pragma unroll
  for (int k = 0; k < 4; ++k) {
    int fi  = tid + k*256;
    int row = fi >> 4;
    int c4  = fi & 15;
    float4 v = *reinterpret_cast<const float4*>(Qbase + (size_t)row*DH_ + c4*4);
    ushort4 h;
    h.x = f2bf(v.x); h.y = f2bf(v.y); h.z = f2bf(v.z); h.w = f2bf(v.w);
    *reinterpret_cast<ushort4*>(&tile[row][c4*4]) = h;
  }
  __syncthreads();

  #pragma unroll
  for (int h2 = 0; h2 < 2; ++h2) {
    int u    = tid + h2*256;
    int blk  = u >> 6;          // 0..7
    int kkl  = blk >> 1;
    int qf   = blk & 1;
    int lane = u & 63;
    int row  = qf*32 + (lane & 31);
    int col  = kkl*16 + (lane >> 5)*8;
    ushort4 h0 = *reinterpret_cast<const ushort4*>(&tile[row][col]);
    ushort4 h1 = *reinterpret_cast<const ushort4*>(&tile[row][col+4]);
    u8* dst = Qf + (size_t)b*8388608 +
              ((((size_t)qt*16 + dt)*8) + kkl*2 + qf)*1024 + lane*16;
    *reinterpret_cast<ushort4*>(dst)     = h0;
    *reinterpret_cast<ushort4*>(dst + 8) = h1;
  }
}

// ================= main: glds-pipelined flash attention =================
// 8 waves; QK: wave w owns s-slice [w*32,+32), C[64q][32s] via 32x32x16.
// PV: wave w owns d [w*128,+128), 32x32x16, Oacc[2 qh][4 dsub].
// K/V staged per-wave via global_load_lds (private LDS dbuf, no staging
// barriers); Q streamed to regs from Qf. l via distributed ones-MFMA.
// launch_bounds (512,1): LDS caps occupancy at 1 block/CU anyway; any
// tighter bound causes total spill (r12-r14 lesson).
__global__ __launch_bounds__(NTH, 1) void attn_glds(
    const u8* __restrict__ Qf, const u8* __restrict__ Kf,
    const u8* __restrict__ Vf, float* __restrict__ Og)
{
  __shared__ __align__(16) u8 kst[65536];
  __shared__ __align__(16) u8 vst[65536];
  __shared__ __align__(16) u8 plds[32768];

  const int tid = threadIdx.x;
  const int w  = tid >> 6;
  const int l  = tid & 63;
  const int sl = l & 31;
  const int sh = l >> 5;

  const int n    = blockIdx.x;
  const int xcd  = n & 7;
  const int slot = n >> 3;
  const int b    = xcd >> 1;
  const int qt   = (xcd & 1)*32 + slot;

  const u8* qfb = Qf + (size_t)b*8388608 + (size_t)qt*131072;
  const u8* kfb = Kf + (size_t)b*8388608;
  const u8* vfb = Vf + (size_t)b*8388608;
  u8* kmy = kst + w*4096;
  u8* vmy = vst + w*4096;

  auto kgl = [&](int t, int c, int buf) {
    const u8* src = kfb + ((((size_t)t*16 + c)*32) + w*4)*1024 + l*16;
    #pragma unroll
    for (int kkl = 0; kkl < 4; ++kkl)
      glds16(src + kkl*1024, kmy + buf*32768 + kkl*1024);
  };
  auto vgl = [&](int t, int ks, int buf) {
    const u8* src = vfb + ((((size_t)t*16 + ks)*32) + w*4)*1024 + l*16;
    #pragma unroll
    for (int ns = 0; ns < 4; ++ns)
      glds16(src + ns*1024, vmy + buf*32768 + ns*1024);
  };
  auto qld = [&](int c, int kkl, int qf) -> bf16x8 {
    return *reinterpret_cast<const bf16x8*>(
        qfb + (((size_t)c*8) + kkl*2 + qf)*1024 + l*16);
  };
  auto bkr = [&](int kkl, int buf) -> bf16x8 {
    return *reinterpret_cast<const bf16x8*>(kmy + buf*32768 + kkl*1024 + l*16);
  };
  auto bvr = [&](int ns, int buf) -> bf16x8 {
    return *reinterpret_cast<const bf16x8*>(vmy + buf*32768 + ns*1024 + l*16);
  };
  auto ldP = [&](int qh, int ks) -> bf16x8 {
    int q = qh*32 + sl;
    return *reinterpret_cast<const bf16x8*>(
        plds + q*512 + ((ks*32 + sh*16) ^ ((q & 7) << 4)));
  };

  f32x16 Oacc[2][4];
  #pragma unroll
  for (int i = 0; i < 2; ++i)
    #pragma unroll
    for (int j = 0; j < 4; ++j)
      #pragma unroll
      for (int r = 0; r < 16; ++r) Oacc[i][j][r] = 0.f;
  f32x16 lacc0, lacc1;
  #pragma unroll
  for (int r = 0; r < 16; ++r) { lacc0[r] = 0.f; lacc1[r] = 0.f; }

  bf16x8 ones;
  #pragma unroll
  for (int e = 0; e < 8; ++e) ones[e] = (__bf16)1.0f;

  f32x16 qk0, qk1;
  bf16x8 aq[8];
  const float SCL = 0.04508422f;   // (1/32)*log2(e)
  const int s2 = (w*32 + sl)*2;

  // prologue: K(0,0) -> kst buf0; aq chunk 0
  kgl(0, 0, 0);
  #pragma unroll
  for (int kkl = 0; kkl < 4; ++kkl) {
    aq[kkl*2+0] = qld(0, kkl, 0);
    aq[kkl*2+1] = qld(0, kkl, 1);
  }
  #pragma unroll
  for (int r = 0; r < 16; ++r) { qk0[r] = 0.f; qk1[r] = 0.f; }

  // ================= period 0: QK(0) only =================
  #pragma unroll
  for (int c = 0; c < 16; ++c) {
    const int buf = c & 1;
    WAITV0(); SCHEDB();
    if (c < 15) kgl(0, c + 1, buf ^ 1);
    else { kgl(1, 0, buf ^ 1); vgl(0, 0, buf ^ 1); }
    const int cn = (c + 1) & 15;
    #pragma unroll
    for (int kkl = 0; kkl < 4; ++kkl) {
      bf16x8 bk = bkr(kkl, buf);
      __builtin_amdgcn_s_setprio(1);
      qk0 = __builtin_amdgcn_mfma_f32_32x32x16_bf16(aq[kkl*2+0], bk, qk0, 0, 0, 0);
      qk1 = __builtin_amdgcn_mfma_f32_32x32x16_bf16(aq[kkl*2+1], bk, qk1, 0, 0, 0);
      __builtin_amdgcn_s_setprio(0);
      aq[kkl*2+0] = qld(cn, kkl, 0);
      aq[kkl*2+1] = qld(cn, kkl, 1);
    }
  }

  // ======== periods t = 1..15: softmax(t-1) + fused QK(t)/PV(t-1) ========
  #pragma unroll 1
  for (int t = 1; t < NT_; ++t) {
    BAR();   // all waves' plds reads of P(t-2) done
    #pragma unroll
    for (int r = 0; r < 16; ++r) {
      int qrow = (r & 3) + 8*(r >> 2) + 4*sh;
      {
        float p = exp2f(qk0[r] * SCL);
        int q = qrow;
        *reinterpret_cast<__bf16*>(plds + q*512 + (s2 ^ ((q & 7) << 4))) = (__bf16)p;
      }
      {
        float p = exp2f(qk1[r] * SCL);
        int q = 32 + qrow;
        *reinterpret_cast<__bf16*>(plds + q*512 + (s2 ^ ((q & 7) << 4))) = (__bf16)p;
      }
    }
    WAITL();
    BAR();   // P(t-1) visible

    #pragma unroll
    for (int r = 0; r < 16; ++r) { qk0[r] = 0.f; qk1[r] = 0.f; }

    #pragma unroll
    for (int c = 0; c < 16; ++c) {
      const int buf = c & 1;
      WAITV0(); SCHEDB();
      if (c < 15)      { kgl(t, c + 1, buf ^ 1); vgl(t - 1, c + 1, buf ^ 1); }
      else             { if (t < 15) kgl(t + 1, 0, buf ^ 1); vgl(t, 0, buf ^ 1); }
      const int cn = (c + 1) & 15;
      // QK chunk c
      #pragma unroll
      for (int kkl = 0; kkl < 4; ++kkl) {
        bf16x8 bk = bkr(kkl, buf);
        __builtin_amdgcn_s_setprio(1);
        qk0 = __builtin_amdgcn_mfma_f32_32x32x16_bf16(aq[kkl*2+0], bk, qk0, 0, 0, 0);
        qk1 = __builtin_amdgcn_mfma_f32_32x32x16_bf16(aq[kkl*2+1], bk, qk1, 0, 0, 0);
        __builtin_amdgcn_s_setprio(0);
        aq[kkl*2+0] = qld(cn, kkl, 0);
        aq[kkl*2+1] = qld(cn, kkl, 1);
      }
      // PV chunk c (tile t-1)
      bf16x8 pa0 = ldP(0, c);
      bf16x8 pa1 = ldP(1, c);
      if ((c >> 1) == w) {     // l: wave w folds P chunks 2w, 2w+1
        lacc0 = __builtin_amdgcn_mfma_f32_32x32x16_bf16(pa0, ones, lacc0, 0, 0, 0);
        lacc1 = __builtin_amdgcn_mfma_f32_32x32x16_bf16(pa1, ones, lacc1, 0, 0, 0);
      }
      __builtin_amdgcn_s_setprio(1);
      #pragma unroll
      for (int ns = 0; ns < 4; ++ns) {
        bf16x8 bv = bvr(ns, buf);
        Oacc[0][ns] = __builtin_amdgcn_mfma_f32_32x32x16_bf16(pa0, bv, Oacc[0][ns], 0, 0, 0);
        Oacc[1][ns] = __builtin_amdgcn_mfma_f32_32x32x16_bf16(pa1, bv, Oacc[1][ns], 0, 0, 0);
      }
      __builtin_amdgcn_s_setprio(0);
    }
  }

  // ================= softmax(15) =================
  BAR();
  #pragma unroll
  for (int r = 0; r < 16; ++r) {
    int qrow = (r & 3) + 8*(r >> 2) + 4*sh;
    {
      float p = exp2f(qk0[r] * SCL);
      int q = qrow;
      *reinterpret_cast<__bf16*>(plds + q*512 + (s2 ^ ((q & 7) << 4))) = (__bf16)p;
    }
    {
      float p = exp2f(qk1[r] * SCL);
      int q = 32 + qrow;
      *reinterpret_cast<__bf16*>(plds + q*512 + (s2 ^ ((q & 7) << 4))) = (__bf16)p;
    }
  }
  WAITL();
  BAR();

  // ================= epilogue period: PV(15) only =================
  #pragma unroll
  for (int c = 0; c < 16; ++c) {
    const int buf = c & 1;
    WAITV0(); SCHEDB();
    if (c < 15) vgl(15, c + 1, buf ^ 1);
    bf16x8 pa0 = ldP(0, c);
    bf16x8 pa1 = ldP(1, c);
    if ((c >> 1) == w) {
      lacc0 = __builtin_amdgcn_mfma_f32_32x32x16_bf16(pa0, ones, lacc0, 0, 0, 0);
      lacc1 = __builtin_amdgcn_mfma_f32_32x32x16_bf16(pa1, ones, lacc1, 0, 0, 0);
    }
    __builtin_amdgcn_s_setprio(1);
    #pragma unroll
    for (int ns = 0; ns < 4; ++ns) {
      bf16x8 bv = bvr(ns, buf);
      Oacc[0][ns] = __builtin_amdgcn_mfma_f32_32x32x16_bf16(pa0, bv, Oacc[0][ns], 0, 0, 0);
      Oacc[1][ns] = __builtin_amdgcn_mfma_f32_32x32x16_bf16(pa1, bv, Oacc[1][ns], 0, 0, 0);
    }
    __builtin_amdgcn_s_setprio(0);
  }
  BAR();   // plds reads done

  // ================= l combine + O write =================
  // lacc D-layout (32x32): col = lane&31 (all cols equal), row = (r&3)+8*(r>>2)+4*sh
  float* lred = (float*)plds;
  if (sl == 0) {
    #pragma unroll
    for (int r = 0; r < 16; ++r) {
      int qrow = (r & 3) + 8*(r >> 2) + 4*sh;
      lred[w*64 + qrow]      = lacc0[r];
      lred[w*64 + 32 + qrow] = lacc1[r];
    }
  }
  WAITL();
  BAR();

  float* Ob = Og + ((size_t)b*LQ_ + (size_t)qt*64)*DH_;
  #pragma unroll
  for (int qh = 0; qh < 2; ++qh)
    #pragma unroll
    for (int r = 0; r < 16; ++r) {
      int q = qh*32 + (r & 3) + 8*(r >> 2) + 4*sh;
      float s = 0.f;
      #pragma unroll
      for (int k2 = 0; k2 < 8; ++k2) s += lred[k2*64 + q];
      float rinv = 1.0f / s;
      #pragma unroll
      for (int ds = 0; ds < 4; ++ds)
        Ob[(size_t)q*DH_ + w*128 + ds*32 + sl] = Oacc[qh][ds][r] * rinv;
    }
}

// =====================================================================
// ============ r11 fallback path (64 MB ws), kept verbatim ============
// =====================================================================
__device__ __forceinline__ bf16x8 cvt8(f32x4 a, f32x4 b) {
  bf16x8 r;
  r[0] = (__bf16)a[0]; r[1] = (__bf16)a[1]; r[2] = (__bf16)a[2]; r[3] = (__bf16)a[3];
  r[4] = (__bf16)b[0]; r[5] = (__bf16)b[1]; r[6] = (__bf16)b[2]; r[7] = (__bf16)b[3];
  return r;
}

__global__ __launch_bounds__(256) void cvt_r11(const float* __restrict__ S,
                                               u8* __restrict__ Kf,
                                               u8* __restrict__ Vf)
{
  __shared__ u16 tile[64][72];
  const int b  = blockIdx.z;
  const int dt = blockIdx.y;
  const int st = blockIdx.x;
  const int tid = threadIdx.x;
  const int t  = st >> 2;
  const float* Sbase = S + ((size_t)b*LS_ + (size_t)st*64)*DH_ + dt*64;

  #pragma unroll
  for (int k = 0; k < 4; ++k) {
    int fi  = tid + k*256;
    int row = fi >> 4;
    int c4  = fi & 15;
    float4 v = *reinterpret_cast<const float4*>(Sbase + (size_t)row*DH_ + c4*4);
    ushort4 h;
    h.x = f2bf(v.x); h.y = f2bf(v.y); h.z = f2bf(v.z); h.w = f2bf(v.w);
    *reinterpret_cast<ushort4*>(&tile[row][c4*4]) = h;
  }
  __syncthreads();

  #pragma unroll
  for (int h2 = 0; h2 < 2; ++h2) {
    int u    = tid + h2*256;
    int blk  = u >> 6;
    int wloc = blk >> 2;
    int kkl  = blk & 3;
    int lane = u & 63;
    int srow = wloc*32 + (lane & 31);
    int scol = kkl*16 + (lane >> 5)*8;
    ushort4 h0 = *reinterpret_cast<const ushort4*>(&tile[srow][scol]);
    ushort4 h1 = *reinterpret_cast<const ushort4*>(&tile[srow][scol+4]);
    int w_g  = (st & 3)*2 + wloc;
    int kk_g = dt*4 + kkl;
    u8* dst = Kf + (size_t)(((b*16 + t)*8 + w_g)*64 + kk_g)*1024 + lane*16;
    *reinterpret_cast<ushort4*>(dst)     = h0;
    *reinterpret_cast<ushort4*>(dst + 8) = h1;
  }

  #pragma unroll
  for (int h2 = 0; h2 < 2; ++h2) {
    int u    = tid + h2*256;
    int blk  = u >> 6;
    int ksl  = blk >> 2;
    int nfl  = blk & 3;
    int lane = u & 63;
    int lg   = (lane >> 4) & 3, lr = lane & 15;
    int srow = ksl*32 + lg*8;
    int dcol = nfl*16 + lr;
    ushort4 h0, h1;
    h0.x = tile[srow+0][dcol]; h0.y = tile[srow+1][dcol];
    h0.z = tile[srow+2][dcol]; h0.w = tile[srow+3][dcol];
    h1.x = tile[srow+4][dcol]; h1.y = tile[srow+5][dcol];
    h1.z = tile[srow+6][dcol]; h1.w = tile[srow+7][dcol];
    int w_g = dt >> 1;
    int i_g = ((st & 3)*2 + ksl)*8 + (dt & 1)*4 + nfl;
    u8* dst = Vf + (size_t)(((b*16 + t)*8 + w_g)*64 + i_g)*1024 + lane*16;
    *reinterpret_cast<ushort4*>(dst)     = h0;
    *reinterpret_cast<ushort4*>(dst + 8) = h1;
  }
}

__global__ __launch_bounds__(NTH, 1) void attn_r11(
    const float* __restrict__ Qg,
    const u8* __restrict__ Kf,
    const u8* __restrict__ Vf,
    float* __restrict__ Og)
{
  __shared__ __align__(16) u8 qlds[131072];
  __shared__ __align__(16) u8 plds[32768];

  const int tid = threadIdx.x;
  const int w  = tid >> 6;
  const int l  = tid & 63;
  const int lg = l >> 4;
  const int lr = l & 15;
  const int sl = l & 31;
  const int sh = l >> 5;

  const int n    = blockIdx.x;
  const int xcd  = n & 7;
  const int slot = n >> 3;
  const int b    = xcd >> 1;
  const int qt   = (xcd & 1)*32 + slot;
  const int off  = slot & 7;

  const float* Qbase = Qg + ((size_t)b*LQ_ + (size_t)qt*64)*DH_;
  const u8* kptr = Kf + (size_t)b*8388608 + (size_t)w*65536 + l*16;
  const u8* vptr = Vf + (size_t)b*8388608 + (size_t)w*65536 + l*16;

  bf16x8 bk[4], bv[4];
  auto ldU = [&](const u8* base, int unit) -> bf16x8 {
    return *reinterpret_cast<const bf16x8*>(base + unit*1024);
  };
  auto ldP = [&](int mq, int ks) -> bf16x8 {
    int q = mq*16 + lr;
    return *reinterpret_cast<const bf16x8*>(
        plds + q*512 + ((ks*64 + lg*16) ^ ((q & 7) << 4)));
  };
  auto ldA = [&](int kk, int qf) -> bf16x8 {
    return *reinterpret_cast<const bf16x8*>(qlds + qf*65536 + kk*1024 + l*16);
  };

  bk[0] = ldU(kptr, off*8 + 0); bk[1] = ldU(kptr, off*8 + 1);
  bk[2] = ldU(kptr, off*8 + 2); bk[3] = ldU(kptr, off*8 + 3);

  #pragma unroll
  for (int it = 0; it < 16; ++it) {
    int u  = tid + it*NTH;
    int qf = u >> 12;
    int kk = (u >> 6) & 63;
    int ll = u & 63;
    int q  = qf*32 + (ll & 31);
    int d  = kk*16 + (ll >> 5)*8;
    const float* p = Qbase + (size_t)q*DH_ + d;
    f32x4 v0 = *reinterpret_cast<const f32x4*>(p);
    f32x4 v1 = *reinterpret_cast<const f32x4*>(p + 4);
    *reinterpret_cast<bf16x8*>(qlds + (size_t)u*16) = cvt8(v0, v1);
  }

  f32x4 Oacc[4][8];
  #pragma unroll
  for (int i = 0; i < 4; ++i)
    #pragma unroll
    for (int j = 0; j < 8; ++j)
      Oacc[i][j] = (f32x4){0.f, 0.f, 0.f, 0.f};
  f32x4 lacc[4];
  #pragma unroll
  for (int i = 0; i < 4; ++i) lacc[i] = (f32x4){0.f, 0.f, 0.f, 0.f};

  bf16x8 ones;
  #pragma unroll
  for (int e = 0; e < 8; ++e) ones[e] = (__bf16)1.0f;

  f32x16 qk0, qk1;
  const float SCL = 0.04508422f;

  WAITL();
  BAR();

  bf16x8 aqA0 = ldA(off*8, 0);
  bf16x8 aqA1 = ldA(off*8, 1);

  #pragma unroll
  for (int r = 0; r < 16; ++r) { qk0[r] = 0.f; qk1[r] = 0.f; }
  #pragma unroll 1
  for (int seg = 0; seg < 8; ++seg) {
    const int ibe = (seg + off) & 7;
    const int ibn = (ibe + 1) & 7;
    const u8* kP = (seg < 7) ? kptr : kptr + 524288;
    #pragma unroll
    for (int j = 0; j < 8; ++j) {
      const int nu = (j < 7) ? (ibe*8 + j + 1) : (ibn*8);
      bf16x8 aqN0 = ldA(nu, 0);
      bf16x8 aqN1 = ldA(nu, 1);
      __builtin_amdgcn_s_setprio(1);
      qk0 = __builtin_amdgcn_mfma_f32_32x32x16_bf16(aqA0, bk[j & 3], qk0, 0, 0, 0);
      qk1 = __builtin_amdgcn_mfma_f32_32x32x16_bf16(aqA1, bk[j & 3], qk1, 0, 0, 0);
      __builtin_amdgcn_s_setprio(0);
      if (j < 4) bk[j] = ldU(kptr, ibe*8 + j + 4);
      else {
        bk[j - 4] = ldU(kP, ibn*8 + j - 4);
        if (seg == 7) bv[j - 4] = ldU(vptr, ibn*8 + j - 4);
      }
      aqA0 = aqN0; aqA1 = aqN1;
    }
  }

  #pragma unroll 1
  for (int t = 1; t < NT_; ++t) {
    BAR();
    #pragma unroll
    for (int r = 0; r < 16; ++r) {
      int qrow = (r & 3) + 8*(r >> 2) + 4*sh;
      int s    = w*32 + sl;
      {
        float p = exp2f(qk0[r] * SCL);
        int q = qrow;
        *reinterpret_cast<__bf16*>(plds + q*512 + ((s*2) ^ ((q & 7) << 4))) = (__bf16)p;
      }
      {
        float p = exp2f(qk1[r] * SCL);
        int q = 32 + qrow;
        *reinterpret_cast<__bf16*>(plds + q*512 + ((s*2) ^ ((q & 7) << 4))) = (__bf16)p;
      }
    }
    WAITL();
    BAR();

    #pragma unroll
    for (int r = 0; r < 16; ++r) { qk0[r] = 0.f; qk1[r] = 0.f; }

    const u8* kT = kptr + (size_t)t*524288;
    const u8* vT = vptr + (size_t)(t-1)*524288;
    bf16x8 pa0, pa1, pa2, pa3;

    #pragma unroll 1
    for (int seg = 0; seg < 8; ++seg) {
      const int ibe = (seg + off) & 7;
      const int ibn = (ibe + 1) & 7;
      const u8* kP = (seg < 7) ? kT : kT + 524288;
      const u8* vP = (seg < 7) ? vT : vT + 524288;
      #pragma unroll
      for (int j = 0; j < 8; ++j) {
        const int nu = (j < 7) ? (ibe*8 + j + 1) : (ibn*8);
        bf16x8 aqN0 = ldA(nu, 0);
        bf16x8 aqN1 = ldA(nu, 1);
        if (j == 0) {
          pa0 = ldP(0, ibe); pa1 = ldP(1, ibe); pa2 = ldP(2, ibe); pa3 = ldP(3, ibe);
          if (ibe == w) {
            lacc[0] = __builtin_amdgcn_mfma_f32_16x16x32_bf16(pa0, ones, lacc[0], 0, 0, 0);
            lacc[1] = __builtin_amdgcn_mfma_f32_16x16x32_bf16(pa1, ones, lacc[1], 0, 0, 0);
            lacc[2] = __builtin_amdgcn_mfma_f32_16x16x32_bf16(pa2, ones, lacc[2], 0, 0, 0);
            lacc[3] = __builtin_amdgcn_mfma_f32_16x16x32_bf16(pa3, ones, lacc[3], 0, 0, 0);
          }
        }
        __builtin_amdgcn_s_setprio(1);
        qk0 = __builtin_amdgcn_mfma_f32_32x32x16_bf16(aqA0, bk[j & 3], qk0, 0, 0, 0);
        qk1 = __builtin_amdgcn_mfma_f32_32x32x16_bf16(aqA1, bk[j & 3], qk1, 0, 0, 0);
        Oacc[0][j] = __builtin_amdgcn_mfma_f32_16x16x32_bf16(pa0, bv[j & 3], Oacc[0][j], 0, 0, 0);
        Oacc[1][j] = __builtin_amdgcn_mfma_f32_16x16x32_bf16(pa1, bv[j & 3], Oacc[1][j], 0, 0, 0);
        Oacc[2][j] = __builtin_amdgcn_mfma_f32_16x16x32_bf16(pa2, bv[j & 3], Oacc[2][j], 0, 0, 0);
        Oacc[3][j] = __builtin_amdgcn_mfma_f32_16x16x32_bf16(pa3, bv[j & 3], Oacc[3][j], 0, 0, 0);
        __builtin_amdgcn_s_setprio(0);
        if (j < 4) {
          bk[j] = ldU(kT, ibe*8 + j + 4);
          bv[j] = ldU(vT, ibe*8 + j + 4);
        } else {
          bk[j - 4] = ldU(kP, ibn*8 + j - 4);
          bv[j - 4] = ldU(vP, ibn*8 + j - 4);
        }
        aqA0 = aqN0; aqA1 = aqN1;
      }
    }
  }

  BAR();
  #pragma unroll
  for (int r = 0; r < 16; ++r) {
    int qrow = (r & 3) + 8*(r >> 2) + 4*sh;
    int s    = w*32 + sl;
    {
      float p = exp2f(qk0[r] * SCL);
      int q = qrow;
      *reinterpret_cast<__bf16*>(plds + q*512 + ((s*2) ^ ((q & 7) << 4))) = (__bf16)p;
    }
    {
      float p = exp2f(qk1[r] * SCL);
      int q = 32 + qrow;
      *reinterpret_cast<__bf16*>(plds + q*512 + ((s*2) ^ ((q & 7) << 4))) = (__bf16)p;
    }
  }
  WAITL();
  BAR();

  {
    const u8* vT = vptr + (size_t)(NT_-1)*524288;
    bf16x8 pa0, pa1, pa2, pa3;
    #pragma unroll 1
    for (int seg = 0; seg < 8; ++seg) {
      const int ibe = (seg + off) & 7;
      const int ibn = (ibe + 1) & 7;
      #pragma unroll
      for (int j = 0; j < 8; ++j) {
        if (j == 0) {
          pa0 = ldP(0, ibe); pa1 = ldP(1, ibe); pa2 = ldP(2, ibe); pa3 = ldP(3, ibe);
          if (ibe == w) {
            lacc[0] = __builtin_amdgcn_mfma_f32_16x16x32_bf16(pa0, ones, lacc[0], 0, 0, 0);
            lacc[1] = __builtin_amdgcn_mfma_f32_16x16x32_bf16(pa1, ones, lacc[1], 0, 0, 0);
            lacc[2] = __builtin_amdgcn_mfma_f32_16x16x32_bf16(pa2, ones, lacc[2], 0, 0, 0);
            lacc[3] = __builtin_amdgcn_mfma_f32_16x16x32_bf16(pa3, ones, lacc[3], 0, 0, 0);
          }
        }
        __builtin_amdgcn_s_setprio(1);
        Oacc[0][j] = __builtin_amdgcn_mfma_f32_16x16x32_bf16(pa0, bv[j & 3], Oacc[0][j], 0, 0, 0);
        Oacc[1][j] = __builtin_amdgcn_mfma_f32_16x16x32_bf16(pa1, bv[j & 3], Oacc[1][j], 0, 0, 0);
        Oacc[2][j] = __builtin_amdgcn_mfma_f32_16x16x32_bf16(pa2, bv[j & 3], Oacc[2][j], 0, 0, 0);
        Oacc[3][j] = __builtin_amdgcn_mfma_f32_16x16x32_bf16(pa3, bv[j & 3], Oacc[3][j], 0, 0, 0);
        __builtin_amdgcn_s_setprio(0);
        if (j < 4)        bv[j] = ldU(vT, ibe*8 + j + 4);
        else if (seg < 7) bv[j - 4] = ldU(vT, ibn*8 + j - 4);
      }
    }
  }
  BAR();

  float* lred = (float*)plds;
  if (lr == 0) {
    #pragma unroll
    for (int mq = 0; mq < 4; ++mq)
      #pragma unroll
      for (int j = 0; j < 4; ++j)
        lred[w*64 + mq*16 + lg*4 + j] = lacc[mq][j];
  }
  WAITL();
  BAR();

  float* Ob = Og + ((size_t)b*LQ_ + (size_t)qt*64)*DH_;
  #pragma unroll
  for (int mq = 0; mq < 4; ++mq)
    #pragma unroll
    for (int j = 0; j < 4; ++j) {
      int q = mq*16 + lg*4 + j;
      float s = 0.f;
      #pragma unroll
      for (int ww = 0; ww < 8; ++ww) s += lred[ww*64 + q];
      float rinv = 1.0f / s;
      #pragma unroll
      for (int nf = 0; nf < 8; ++nf)
        Ob[(size_t)q*DH_ + w*128 + nf*16 + lr] = Oacc[mq][nf][j] * rinv;
    }
}

// ---------------- correctness-only fallback ----------------
__global__ void attn_naive(const float* __restrict__ Q, const float* __restrict__ S,
                           float* __restrict__ O)
{
  const int row = blockIdx.x;
  const int b = row >> 12, q = row & 4095;
  const float* qp = Q + ((size_t)b*LQ_ + q)*DH_;
  const float* sp = S + (size_t)b*LS_*DH_;
  __shared__ float qs[DH_];
  __shared__ float osum[DH_];
  __shared__ float lsum;
  for (int i = threadIdx.x; i < DH_; i += 256) { qs[i] = qp[i]; osum[i] = 0.f; }
  if (threadIdx.x == 0) lsum = 0.f;
  __syncthreads();
  float lpart = 0.f;
  for (int s0 = threadIdx.x; s0 < LS_; s0 += 256) {
    const float* sr = sp + (size_t)s0*DH_;
    float dot = 0.f;
    for (int d = 0; d < DH_; ++d) dot += qs[d]*sr[d];
    float p = __expf(dot * 0.03125f);
    lpart += p;
    for (int d = 0; d < DH_; ++d) atomicAdd(&osum[d], p*sr[d]);
  }
  atomicAdd(&lsum, lpart);
  __syncthreads();
  float rinv = 1.0f / lsum;
  float* op = O + ((size_t)b*LQ_ + q)*DH_;
  for (int i = threadIdx.x; i < DH_; i += 256) op[i] = osum[i]*rinv;
}

extern "C" void kernel_launch(void* const* d_in, const int* in_sizes, int n_in,
                              void* d_out, int out_size, void* d_ws, size_t ws_size,
                              hipStream_t stream)
{
  const float* Q = (const float*)d_in[0];
  const float* S = (const float*)d_in[1];
  float* out = (float*)d_out;

  const size_t seg = (size_t)B_*8388608;        // 32 MiB per tensor
  const size_t need_new = 3*seg;                // Qf + Kf + Vf = 96 MiB
  const size_t need_old = 2*seg;                // 64 MiB

  if (ws_size >= need_new) {
    u8* Qf  = (u8*)d_ws;
    u8* Kf2 = Qf + seg;
    u8* Vf2 = Kf2 + seg;
    qcvt_kernel<<<dim3(64, 16, 4), 256, 0, stream>>>(Q, Qf);
    scvt_kernel<<<dim3(64, 16, 4), 256, 0, stream>>>(S, Kf2, Vf2);
    attn_glds<<<dim3(256), NTH, 0, stream>>>(Qf, Kf2, Vf2, out);
  } else if (ws_size >= need_old) {
    u8* Kf = (u8*)d_ws;
    u8* Vf = Kf + seg;
    cvt_r11<<<dim3(64, 16, 4), 256, 0, stream>>>(S, Kf, Vf);
    attn_r11<<<dim3(256), NTH, 0, stream>>>(Q, Kf, Vf, out);
  } else {
    attn_naive<<<dim3(B_*LQ_), 256, 0, stream>>>(Q, S, out);
  }
}

// Round 16
// 302.567 us; speedup vs baseline: 12.1981x; 4.8574x over previous
//
#include <hip/hip_runtime.h>
#include <hip/hip_bf16.h>

#define B_   4
#define LQ_  4096
#define LS_  4096
#define DH_  1024
#define BQ_  64
#define BS_  256
#define NT_  (LS_/BS_)   /* 16 */
#define NTH  512

typedef __bf16 bf16x8 __attribute__((ext_vector_type(8)));
typedef float  f32x4  __attribute__((ext_vector_type(4)));
typedef float  f32x16 __attribute__((ext_vector_type(16)));
typedef unsigned char u8;

#define WAITL()  asm volatile("s_waitcnt lgkmcnt(0)" ::: "memory")
#define BAR()    __builtin_amdgcn_s_barrier()

__device__ __forceinline__ unsigned short f2bf(float f) {
  union { __bf16 h; unsigned short u; } cv;
  cv.h = (__bf16)f;
  return cv.u;
}
__device__ __forceinline__ bf16x8 cvt8(f32x4 a, f32x4 b) {
  bf16x8 r;
  r[0] = (__bf16)a[0]; r[1] = (__bf16)a[1]; r[2] = (__bf16)a[2]; r[3] = (__bf16)a[3];
  r[4] = (__bf16)b[0]; r[5] = (__bf16)b[1]; r[6] = (__bf16)b[2]; r[7] = (__bf16)b[3];
  return r;
}

// ---- fp32 S -> fragment-major bf16 layouts (wave-contiguous 1KB ring loads) ----
__global__ __launch_bounds__(256) void cvt_kernel(const float* __restrict__ S,
                                                  u8* __restrict__ Kf,
                                                  u8* __restrict__ Vf)
{
  __shared__ unsigned short tile[64][72];
  const int b  = blockIdx.z;
  const int dt = blockIdx.y;   // 0..15  (64 d each)
  const int st = blockIdx.x;   // 0..63  (64 s each)
  const int tid = threadIdx.x;
  const int t  = st >> 2;
  const float* Sbase = S + ((size_t)b*LS_ + (size_t)st*64)*DH_ + dt*64;

  #pragma unroll
  for (int k = 0; k < 4; ++k) {
    int fi  = tid + k*256;
    int row = fi >> 4;
    int c4  = fi & 15;
    float4 v = *reinterpret_cast<const float4*>(Sbase + (size_t)row*DH_ + c4*4);
    ushort4 h;
    h.x = f2bf(v.x); h.y = f2bf(v.y); h.z = f2bf(v.z); h.w = f2bf(v.w);
    *reinterpret_cast<ushort4*>(&tile[row][c4*4]) = h;
  }
  __syncthreads();

  // Kf: 8x 1KB blocks
  #pragma unroll
  for (int h2 = 0; h2 < 2; ++h2) {
    int u    = tid + h2*256;
    int blk  = u >> 6;
    int wloc = blk >> 2;
    int kkl  = blk & 3;
    int lane = u & 63;
    int sh   = lane >> 5, sl = lane & 31;
    int srow = wloc*32 + sl;
    int scol = kkl*16 + sh*8;
    ushort4 h0 = *reinterpret_cast<const ushort4*>(&tile[srow][scol]);
    ushort4 h1 = *reinterpret_cast<const ushort4*>(&tile[srow][scol+4]);
    int w_g  = (st & 3)*2 + wloc;
    int kk_g = dt*4 + kkl;
    u8* dst = Kf + (size_t)(((b*16 + t)*8 + w_g)*64 + kk_g)*1024 + lane*16;
    *reinterpret_cast<ushort4*>(dst)     = h0;
    *reinterpret_cast<ushort4*>(dst + 8) = h1;
  }

  // Vf: 8x 1KB blocks (transposed gather)
  #pragma unroll
  for (int h2 = 0; h2 < 2; ++h2) {
    int u    = tid + h2*256;
    int blk  = u >> 6;
    int ksl  = blk >> 2;
    int nfl  = blk & 3;
    int lane = u & 63;
    int lg   = lane >> 4, lr = lane & 15;
    int srow = ksl*32 + lg*8;
    int dcol = nfl*16 + lr;
    ushort4 h0, h1;
    h0.x = tile[srow+0][dcol]; h0.y = tile[srow+1][dcol];
    h0.z = tile[srow+2][dcol]; h0.w = tile[srow+3][dcol];
    h1.x = tile[srow+4][dcol]; h1.y = tile[srow+5][dcol];
    h1.z = tile[srow+6][dcol]; h1.w = tile[srow+7][dcol];
    int w_g = dt >> 1;
    int i_g = ((st & 3)*2 + ksl)*8 + (dt & 1)*4 + nfl;
    u8* dst = Vf + (size_t)(((b*16 + t)*8 + w_g)*64 + i_g)*1024 + lane*16;
    *reinterpret_cast<ushort4*>(dst)     = h0;
    *reinterpret_cast<ushort4*>(dst + 8) = h1;
  }
}

// ---------------- fused flash attention, m==0 softmax, cross-tile pipelined ----------------
// Fused QK^T(t) + PV(t-1) in one instruction stream; partial unroll (8-wide
// bodies, outer loops rolled) keeps hot code ~7 KB -> I$-resident.
__global__ __launch_bounds__(NTH, 1) void attn_kernel(
    const float* __restrict__ Qg,
    const u8* __restrict__ Kf,
    const u8* __restrict__ Vf,
    float* __restrict__ Og)
{
  __shared__ __align__(16) unsigned char qlds[131072];  // [qf:2][kk:64][lane:64]*16B
  __shared__ __align__(16) unsigned char plds[32768];   // P [64 q][256 s] bf16 swizzled

  const int tid = threadIdx.x;
  const int w  = tid >> 6;
  const int l  = tid & 63;
  const int lg = l >> 4;
  const int lr = l & 15;
  const int sl = l & 31;
  const int sh = l >> 5;

  const int n    = blockIdx.x;
  const int xcd  = n & 7;
  const int slot = n >> 3;
  const int b    = xcd >> 1;
  const int qt   = (xcd & 1)*32 + slot;

  const float* Qbase = Qg + ((size_t)b*LQ_ + (size_t)qt*BQ_)*DH_;
  const u8* kptr = Kf + (size_t)b*8388608 + (size_t)w*65536 + l*16;
  const u8* vptr = Vf + (size_t)b*8388608 + (size_t)w*65536 + l*16;

  bf16x8 bk[4];
  auto ld_bk = [&](int t, int kk) -> bf16x8 {
    return *reinterpret_cast<const bf16x8*>(kptr + (size_t)t*524288 + kk*1024);
  };
  bf16x8 bv[4];
  auto ld_bv = [&](int t, int i) -> bf16x8 {
    return *reinterpret_cast<const bf16x8*>(vptr + (size_t)t*524288 + i*1024);
  };
  auto ldP = [&](int mq, int ks) -> bf16x8 {
    int q = mq*16 + lr;
    return *reinterpret_cast<const bf16x8*>(
        plds + q*512 + ((ks*64 + lg*16) ^ ((q & 7) << 4)));
  };

  // K-ring prologue for t=0 (in flight across Q staging)
  bk[0] = ld_bk(0, 0); bk[1] = ld_bk(0, 1); bk[2] = ld_bk(0, 2);

  // ---- stage Q fp32 -> bf16 into lane-linear fragment layout (once) ----
  #pragma unroll
  for (int it = 0; it < 16; ++it) {
    int u  = tid + it*NTH;
    int qf = u >> 12;
    int kk = (u >> 6) & 63;
    int ll = u & 63;
    int q  = qf*32 + (ll & 31);
    int d  = kk*16 + (ll >> 5)*8;
    const float* p = Qbase + (size_t)q*DH_ + d;
    f32x4 v0 = *reinterpret_cast<const f32x4*>(p);
    f32x4 v1 = *reinterpret_cast<const f32x4*>(p + 4);
    *reinterpret_cast<bf16x8*>(qlds + (size_t)u*16) = cvt8(v0, v1);
  }

  f32x4 Oacc[4][8];
  #pragma unroll
  for (int i = 0; i < 4; ++i)
    #pragma unroll
    for (int j = 0; j < 8; ++j)
      Oacc[i][j] = (f32x4){0.f, 0.f, 0.f, 0.f};
  f32x4 lacc[4];
  #pragma unroll
  for (int i = 0; i < 4; ++i) lacc[i] = (f32x4){0.f, 0.f, 0.f, 0.f};

  bf16x8 ones;
  #pragma unroll
  for (int e = 0; e < 8; ++e) ones[e] = (__bf16)1.0f;

  f32x16 qk0, qk1;
  const float SCL = 0.04508422f;   // (1/32) * log2(e)

  WAITL();
  BAR();   // Q staged

  // ================= QK-only prologue: tile 0 =================
  #pragma unroll
  for (int r = 0; r < 16; ++r) { qk0[r] = 0.f; qk1[r] = 0.f; }
  {
    bf16x8 aqA0 = *reinterpret_cast<const bf16x8*>(qlds + l*16);
    bf16x8 aqA1 = *reinterpret_cast<const bf16x8*>(qlds + 65536 + l*16);
    #pragma unroll 1
    for (int ib = 0; ib < 7; ++ib) {
      #pragma unroll
      for (int j = 0; j < 8; ++j) {
        const int kk = ib*8 + j;                      // 0..55
        bk[(j + 3) & 3] = ld_bk(0, kk + 3);
        bf16x8 aqN0 = *reinterpret_cast<const bf16x8*>(qlds + (kk + 1)*1024 + l*16);
        bf16x8 aqN1 = *reinterpret_cast<const bf16x8*>(qlds + 65536 + (kk + 1)*1024 + l*16);
        qk0 = __builtin_amdgcn_mfma_f32_32x32x16_bf16(aqA0, bk[j & 3], qk0, 0, 0, 0);
        qk1 = __builtin_amdgcn_mfma_f32_32x32x16_bf16(aqA1, bk[j & 3], qk1, 0, 0, 0);
        aqA0 = aqN0; aqA1 = aqN1;
      }
    }
    #pragma unroll
    for (int j = 56; j < 64; ++j) {                   // static tail
      if (j < 61) bk[(j + 3) & 3] = ld_bk(0, j + 3);
      bf16x8 aqN0, aqN1;
      if (j < 63) {
        aqN0 = *reinterpret_cast<const bf16x8*>(qlds + (j + 1)*1024 + l*16);
        aqN1 = *reinterpret_cast<const bf16x8*>(qlds + 65536 + (j + 1)*1024 + l*16);
      }
      qk0 = __builtin_amdgcn_mfma_f32_32x32x16_bf16(aqA0, bk[j & 3], qk0, 0, 0, 0);
      qk1 = __builtin_amdgcn_mfma_f32_32x32x16_bf16(aqA1, bk[j & 3], qk1, 0, 0, 0);
      if (j < 63) { aqA0 = aqN0; aqA1 = aqN1; }
    }
  }

  // ================= main: for t = 1..15, fused QK(t) + PV(t-1) =================
  #pragma unroll 1
  for (int t = 1; t < NT_; ++t) {
    BAR();   // all waves' plds reads of P(t-2) done

    // softmax(t-1): P = exp2(scl*logit) -> plds
    #pragma unroll
    for (int r = 0; r < 16; ++r) {
      int qrow = (r & 3) + 8*(r >> 2) + 4*sh;
      int s    = w*32 + sl;
      {
        float p = exp2f(qk0[r] * SCL);
        int q = qrow;
        *reinterpret_cast<__bf16*>(plds + q*512 + ((s*2) ^ ((q & 7) << 4))) = (__bf16)p;
      }
      {
        float p = exp2f(qk1[r] * SCL);
        int q = 32 + qrow;
        *reinterpret_cast<__bf16*>(plds + q*512 + ((s*2) ^ ((q & 7) << 4))) = (__bf16)p;
      }
    }

    // ring prologues (latency hidden under softmax + barrier)
    bk[0] = ld_bk(t, 0); bk[1] = ld_bk(t, 1); bk[2] = ld_bk(t, 2);
    bv[0] = ld_bv(t-1, 0); bv[1] = ld_bv(t-1, 1); bv[2] = ld_bv(t-1, 2);

    WAITL();
    BAR();   // P(t-1) visible

    #pragma unroll
    for (int r = 0; r < 16; ++r) { qk0[r] = 0.f; qk1[r] = 0.f; }

    bf16x8 aqA0 = *reinterpret_cast<const bf16x8*>(qlds + l*16);
    bf16x8 aqA1 = *reinterpret_cast<const bf16x8*>(qlds + 65536 + l*16);
    bf16x8 pa0, pa1, pa2, pa3;

    #pragma unroll 1
    for (int ib = 0; ib < 7; ++ib) {
      #pragma unroll
      for (int j = 0; j < 8; ++j) {
        const int i = ib*8 + j;                       // 0..55
        // ---- QK(t) ----
        bk[(j + 3) & 3] = ld_bk(t, i + 3);
        bf16x8 aqN0 = *reinterpret_cast<const bf16x8*>(qlds + (i + 1)*1024 + l*16);
        bf16x8 aqN1 = *reinterpret_cast<const bf16x8*>(qlds + 65536 + (i + 1)*1024 + l*16);
        qk0 = __builtin_amdgcn_mfma_f32_32x32x16_bf16(aqA0, bk[j & 3], qk0, 0, 0, 0);
        qk1 = __builtin_amdgcn_mfma_f32_32x32x16_bf16(aqA1, bk[j & 3], qk1, 0, 0, 0);
        aqA0 = aqN0; aqA1 = aqN1;
        // ---- PV(t-1) ----
        bv[(j + 3) & 3] = ld_bv(t-1, i + 3);
        if (j == 0) {
          pa0 = ldP(0, ib); pa1 = ldP(1, ib); pa2 = ldP(2, ib); pa3 = ldP(3, ib);
          if (w == 0) {
            lacc[0] = __builtin_amdgcn_mfma_f32_16x16x32_bf16(pa0, ones, lacc[0], 0, 0, 0);
            lacc[1] = __builtin_amdgcn_mfma_f32_16x16x32_bf16(pa1, ones, lacc[1], 0, 0, 0);
            lacc[2] = __builtin_amdgcn_mfma_f32_16x16x32_bf16(pa2, ones, lacc[2], 0, 0, 0);
            lacc[3] = __builtin_amdgcn_mfma_f32_16x16x32_bf16(pa3, ones, lacc[3], 0, 0, 0);
          }
        }
        Oacc[0][j] = __builtin_amdgcn_mfma_f32_16x16x32_bf16(pa0, bv[j & 3], Oacc[0][j], 0, 0, 0);
        Oacc[1][j] = __builtin_amdgcn_mfma_f32_16x16x32_bf16(pa1, bv[j & 3], Oacc[1][j], 0, 0, 0);
        Oacc[2][j] = __builtin_amdgcn_mfma_f32_16x16x32_bf16(pa2, bv[j & 3], Oacc[2][j], 0, 0, 0);
        Oacc[3][j] = __builtin_amdgcn_mfma_f32_16x16x32_bf16(pa3, bv[j & 3], Oacc[3][j], 0, 0, 0);
      }
    }
    #pragma unroll
    for (int j = 56; j < 64; ++j) {                   // static tail, i = j
      const int nf = j & 7;
      if (j < 61) bk[(j + 3) & 3] = ld_bk(t, j + 3);
      bf16x8 aqN0, aqN1;
      if (j < 63) {
        aqN0 = *reinterpret_cast<const bf16x8*>(qlds + (j + 1)*1024 + l*16);
        aqN1 = *reinterpret_cast<const bf16x8*>(qlds + 65536 + (j + 1)*1024 + l*16);
      }
      qk0 = __builtin_amdgcn_mfma_f32_32x32x16_bf16(aqA0, bk[j & 3], qk0, 0, 0, 0);
      qk1 = __builtin_amdgcn_mfma_f32_32x32x16_bf16(aqA1, bk[j & 3], qk1, 0, 0, 0);
      if (j < 63) { aqA0 = aqN0; aqA1 = aqN1; }
      if (j < 61) bv[(j + 3) & 3] = ld_bv(t-1, j + 3);
      if (nf == 0) {
        pa0 = ldP(0, 7); pa1 = ldP(1, 7); pa2 = ldP(2, 7); pa3 = ldP(3, 7);
        if (w == 0) {
          lacc[0] = __builtin_amdgcn_mfma_f32_16x16x32_bf16(pa0, ones, lacc[0], 0, 0, 0);
          lacc[1] = __builtin_amdgcn_mfma_f32_16x16x32_bf16(pa1, ones, lacc[1], 0, 0, 0);
          lacc[2] = __builtin_amdgcn_mfma_f32_16x16x32_bf16(pa2, ones, lacc[2], 0, 0, 0);
          lacc[3] = __builtin_amdgcn_mfma_f32_16x16x32_bf16(pa3, ones, lacc[3], 0, 0, 0);
        }
      }
      Oacc[0][nf] = __builtin_amdgcn_mfma_f32_16x16x32_bf16(pa0, bv[j & 3], Oacc[0][nf], 0, 0, 0);
      Oacc[1][nf] = __builtin_amdgcn_mfma_f32_16x16x32_bf16(pa1, bv[j & 3], Oacc[1][nf], 0, 0, 0);
      Oacc[2][nf] = __builtin_amdgcn_mfma_f32_16x16x32_bf16(pa2, bv[j & 3], Oacc[2][nf], 0, 0, 0);
      Oacc[3][nf] = __builtin_amdgcn_mfma_f32_16x16x32_bf16(pa3, bv[j & 3], Oacc[3][nf], 0, 0, 0);
    }
  }

  // ================= epilogue: softmax(15) + PV-only =================
  BAR();
  #pragma unroll
  for (int r = 0; r < 16; ++r) {
    int qrow = (r & 3) + 8*(r >> 2) + 4*sh;
    int s    = w*32 + sl;
    {
      float p = exp2f(qk0[r] * SCL);
      int q = qrow;
      *reinterpret_cast<__bf16*>(plds + q*512 + ((s*2) ^ ((q & 7) << 4))) = (__bf16)p;
    }
    {
      float p = exp2f(qk1[r] * SCL);
      int q = 32 + qrow;
      *reinterpret_cast<__bf16*>(plds + q*512 + ((s*2) ^ ((q & 7) << 4))) = (__bf16)p;
    }
  }
  bv[0] = ld_bv(NT_-1, 0); bv[1] = ld_bv(NT_-1, 1); bv[2] = ld_bv(NT_-1, 2);
  WAITL();
  BAR();

  {
    bf16x8 pa0, pa1, pa2, pa3;
    #pragma unroll 1
    for (int ib = 0; ib < 7; ++ib) {
      #pragma unroll
      for (int j = 0; j < 8; ++j) {
        const int i = ib*8 + j;                       // 0..55
        bv[(j + 3) & 3] = ld_bv(NT_-1, i + 3);
        if (j == 0) {
          pa0 = ldP(0, ib); pa1 = ldP(1, ib); pa2 = ldP(2, ib); pa3 = ldP(3, ib);
          if (w == 0) {
            lacc[0] = __builtin_amdgcn_mfma_f32_16x16x32_bf16(pa0, ones, lacc[0], 0, 0, 0);
            lacc[1] = __builtin_amdgcn_mfma_f32_16x16x32_bf16(pa1, ones, lacc[1], 0, 0, 0);
            lacc[2] = __builtin_amdgcn_mfma_f32_16x16x32_bf16(pa2, ones, lacc[2], 0, 0, 0);
            lacc[3] = __builtin_amdgcn_mfma_f32_16x16x32_bf16(pa3, ones, lacc[3], 0, 0, 0);
          }
        }
        Oacc[0][j] = __builtin_amdgcn_mfma_f32_16x16x32_bf16(pa0, bv[j & 3], Oacc[0][j], 0, 0, 0);
        Oacc[1][j] = __builtin_amdgcn_mfma_f32_16x16x32_bf16(pa1, bv[j & 3], Oacc[1][j], 0, 0, 0);
        Oacc[2][j] = __builtin_amdgcn_mfma_f32_16x16x32_bf16(pa2, bv[j & 3], Oacc[2][j], 0, 0, 0);
        Oacc[3][j] = __builtin_amdgcn_mfma_f32_16x16x32_bf16(pa3, bv[j & 3], Oacc[3][j], 0, 0, 0);
      }
    }
    #pragma unroll
    for (int j = 56; j < 64; ++j) {                   // static tail
      const int nf = j & 7;
      if (j < 61) bv[(j + 3) & 3] = ld_bv(NT_-1, j + 3);
      if (nf == 0) {
        pa0 = ldP(0, 7); pa1 = ldP(1, 7); pa2 = ldP(2, 7); pa3 = ldP(3, 7);
        if (w == 0) {
          lacc[0] = __builtin_amdgcn_mfma_f32_16x16x32_bf16(pa0, ones, lacc[0], 0, 0, 0);
          lacc[1] = __builtin_amdgcn_mfma_f32_16x16x32_bf16(pa1, ones, lacc[1], 0, 0, 0);
          lacc[2] = __builtin_amdgcn_mfma_f32_16x16x32_bf16(pa2, ones, lacc[2], 0, 0, 0);
          lacc[3] = __builtin_amdgcn_mfma_f32_16x16x32_bf16(pa3, ones, lacc[3], 0, 0, 0);
        }
      }
      Oacc[0][nf] = __builtin_amdgcn_mfma_f32_16x16x32_bf16(pa0, bv[j & 3], Oacc[0][nf], 0, 0, 0);
      Oacc[1][nf] = __builtin_amdgcn_mfma_f32_16x16x32_bf16(pa1, bv[j & 3], Oacc[1][nf], 0, 0, 0);
      Oacc[2][nf] = __builtin_amdgcn_mfma_f32_16x16x32_bf16(pa2, bv[j & 3], Oacc[2][nf], 0, 0, 0);
      Oacc[3][nf] = __builtin_amdgcn_mfma_f32_16x16x32_bf16(pa3, bv[j & 3], Oacc[3][nf], 0, 0, 0);
    }
  }
  BAR();

  // ================= l from wave-0 ones-MFMA, write O =================
  float* lred = (float*)plds;
  if (w == 0 && lr == 0) {
    #pragma unroll
    for (int mq = 0; mq < 4; ++mq)
      #pragma unroll
      for (int j = 0; j < 4; ++j)
        lred[mq*16 + lg*4 + j] = lacc[mq][j];
  }
  WAITL();
  BAR();

  float* Ob = Og + ((size_t)b*LQ_ + (size_t)qt*BQ_)*DH_;
  #pragma unroll
  for (int mq = 0; mq < 4; ++mq)
    #pragma unroll
    for (int j = 0; j < 4; ++j) {
      int q = mq*16 + lg*4 + j;
      float rinv = 1.0f / lred[q];
      #pragma unroll
      for (int nf = 0; nf < 8; ++nf)
        Ob[(size_t)q*DH_ + w*128 + nf*16 + lr] = Oacc[mq][nf][j] * rinv;
    }
}

// ---------------- correctness-only fallback (ws too small; never expected) ----------------
__global__ void attn_naive(const float* __restrict__ Q, const float* __restrict__ S,
                           float* __restrict__ O)
{
  const int row = blockIdx.x;
  const int b = row >> 12, q = row & 4095;
  const float* qp = Q + ((size_t)b*LQ_ + q)*DH_;
  const float* sp = S + (size_t)b*LS_*DH_;
  __shared__ float qs[DH_];
  __shared__ float osum[DH_];
  __shared__ float lsum;
  for (int i = threadIdx.x; i < DH_; i += 256) { qs[i] = qp[i]; osum[i] = 0.f; }
  if (threadIdx.x == 0) lsum = 0.f;
  __syncthreads();
  float lpart = 0.f;
  for (int s0 = threadIdx.x; s0 < LS_; s0 += 256) {
    const float* sr = sp + (size_t)s0*DH_;
    float dot = 0.f;
    for (int d = 0; d < DH_; ++d) dot += qs[d]*sr[d];
    float p = __expf(dot * 0.03125f);
    lpart += p;
    for (int d = 0; d < DH_; ++d) atomicAdd(&osum[d], p*sr[d]);
  }
  atomicAdd(&lsum, lpart);
  __syncthreads();
  float rinv = 1.0f / lsum;
  float* op = O + ((size_t)b*LQ_ + q)*DH_;
  for (int i = threadIdx.x; i < DH_; i += 256) op[i] = osum[i]*rinv;
}

extern "C" void kernel_launch(void* const* d_in, const int* in_sizes, int n_in,
                              void* d_out, int out_size, void* d_ws, size_t ws_size,
                              hipStream_t stream)
{
  const float* Q = (const float*)d_in[0];
  const float* S = (const float*)d_in[1];
  float* out = (float*)d_out;

  const size_t kf_bytes = (size_t)B_*NT_*8*64*1024;   // 32 MiB (bf16)
  const size_t vf_bytes = (size_t)B_*NT_*8*64*1024;   // 32 MiB (bf16)
  const size_t need = kf_bytes + vf_bytes;            // 64 MiB

  if (ws_size >= need) {
    u8* Kf = (u8*)d_ws;
    u8* Vf = Kf + kf_bytes;
    cvt_kernel<<<dim3(64, 16, 4), 256, 0, stream>>>(S, Kf, Vf);
    attn_kernel<<<dim3(256), NTH, 0, stream>>>(Q, Kf, Vf, out);
  } else {
    attn_naive<<<dim3(B_*LQ_), 256, 0, stream>>>(Q, S, out);
  }
}